// Round 11
// baseline (96.231 us; speedup 1.0000x reference)
//
#include <hip/hip_runtime.h>
#include <hip/hip_bf16.h>
#include <math.h>

#define N_STATES 32768
#define N_LABELS 64
#define N_BATCH  512

// ws float layout: Zp[8][64][64] @ ZP_F ; Up[8][64][64][64] @ UP_F.
// Per-block PRIVATE partials -> plain stores, no atomics, no init, and the
// fused->finalize handoff rides a dispatch boundary (the only cross-XCD
// coherence mechanism verified to work here; rounds 8-10's in-kernel fence
// barriers all failed on XCD L2 non-coherence).
#define ZP_F     1024
#define UP_F     65536

typedef __attribute__((ext_vector_type(8))) short bfrag;
typedef __attribute__((ext_vector_type(4))) float f32x4;

static __device__ __forceinline__ unsigned short f2bf(float x) {
    __hip_bfloat16 h = __float2bfloat16(x);
    return *reinterpret_cast<unsigned short*>(&h);
}
static __device__ __forceinline__ float bf2f(unsigned short u) {
    __hip_bfloat16 h;
    *reinterpret_cast<unsigned short*>(&h) = u;
    return __bfloat162float(h);
}

// ---------------------------------------------------------------------------
// Fused GEMM1 + exp + GEMM2, NO prep kernel, NO LDS in the K-loop.
// Grid 512, XCD-affine: btile=blockIdx>>6, chunk=blockIdx&63 (chunk%8 -> XCD,
// per-XCD S working set = 8 chunks x 128 KB fp32 = 1 MB, L2-resident across
// the 8 btile re-reads).
// S is 0/1 -> EXACT in bf16, so both operand layouts are built in-register
// straight from global fp32 S:
//   GEMM1 A (rows):    4 float4 loads/lane/tile, immediate offsets.
//   GEMM2 A (columns): 16 dword gathers/lane/tile; each instr touches 4
//                      fully-used 64B lines (x-lanes contiguous), L2-local.
// f enters as hi/lo bf16 split (~fp32 accuracy); E never leaves registers
// (GEMM1 C-frag == GEMM2 B-frag identity, j>=4 zero-padded both sides);
// per-wave 64x64 U partial in 64 VGPRs; LDS only in the epilogue merge.
// M[b] = sum_i max(f,0) bound (softmax shift-invariance: exact).
__global__ __launch_bounds__(256, 2) void fused_kernel(
    const float* __restrict__ f, const float* __restrict__ S,
    float* __restrict__ ws, float* __restrict__ out) {
    __shared__ alignas(16) unsigned char smem[66560];   // epilogue merge only

    const int t     = threadIdx.x;
    const int lane  = t & 63;
    const int w     = t >> 6;
    const int x     = lane & 15;
    const int quad  = lane >> 4;
    const int btile = blockIdx.x >> 6;
    const int chunk = blockIdx.x & 63;

    // ---- f B-frags (hi/lo split) + M[b] via quad butterfly (round 7 code)
    bfrag fh[4][2], fl[4][2];
    float Mv[4];
    #pragma unroll
    for (int nt = 0; nt < 4; nt++) {
        const float4* fp = reinterpret_cast<const float4*>(
            f + ((size_t)(btile * 64 + nt * 16 + x)) * N_LABELS);
        float msum = 0.f;
        #pragma unroll
        for (int kh = 0; kh < 2; kh++) {
            float4 a = fp[kh * 8 + quad * 2];
            float4 b = fp[kh * 8 + quad * 2 + 1];
            float vv[8] = {a.x,a.y,a.z,a.w, b.x,b.y,b.z,b.w};
            #pragma unroll
            for (int j = 0; j < 8; j++) {
                msum += fmaxf(vv[j], 0.f);
                unsigned short h = f2bf(vv[j]);
                fh[nt][kh][j] = (short)h;
                fl[nt][kh][j] = (short)f2bf(vv[j] - bf2f(h));
            }
        }
        msum += __shfl_xor(msum, 16, 64);
        msum += __shfl_xor(msum, 32, 64);
        Mv[nt] = msum;
    }

    f32x4 Uacc[16];   // [it*4+nt]: U(i=it*16+quad*4+r, b=nt*16+x)
    #pragma unroll
    for (int e = 0; e < 16; e++) Uacc[e] = (f32x4){0.f, 0.f, 0.f, 0.f};
    float zacc[4] = {0.f, 0.f, 0.f, 0.f};

    #pragma unroll
    for (int st = 0; st < 8; st++) {
        const int s0 = (chunk * 8 + st) * 64;

        // ---- GEMM1 A: row s0+16w+x, labels quad*8..+8 and +32 (exact bf16)
        const float* Arow = S + (size_t)(s0 + 16 * w + x) * N_LABELS + quad * 8;
        float4 r0 = *(const float4*)(Arow);
        float4 r1 = *(const float4*)(Arow + 4);
        float4 r2 = *(const float4*)(Arow + 32);
        float4 r3 = *(const float4*)(Arow + 36);
        bfrag a0 = {(short)f2bf(r0.x), (short)f2bf(r0.y), (short)f2bf(r0.z), (short)f2bf(r0.w),
                    (short)f2bf(r1.x), (short)f2bf(r1.y), (short)f2bf(r1.z), (short)f2bf(r1.w)};
        bfrag a1 = {(short)f2bf(r2.x), (short)f2bf(r2.y), (short)f2bf(r2.z), (short)f2bf(r2.w),
                    (short)f2bf(r3.x), (short)f2bf(r3.y), (short)f2bf(r3.z), (short)f2bf(r3.w)};

        // ---- GEMM2 A: S^T[i=16it+x][s=s0+16w+4quad+j], j<4; one base + 16
        //      immediate-offset dword loads (offset (j*64+it*16)*4 <= 960 B)
        const float* Acol = S + (size_t)(s0 + 16 * w + 4 * quad) * N_LABELS + x;
        bfrag A8[4];
        #pragma unroll
        for (int it = 0; it < 4; it++) {
            float c0 = Acol[0 * 64 + it * 16];
            float c1 = Acol[1 * 64 + it * 16];
            float c2 = Acol[2 * 64 + it * 16];
            float c3 = Acol[3 * 64 + it * 16];
            bfrag tmp = {(short)f2bf(c0), (short)f2bf(c1),
                         (short)f2bf(c2), (short)f2bf(c3), 0, 0, 0, 0};
            A8[it] = tmp;
        }

        #pragma unroll
        for (int nt = 0; nt < 4; nt++) {
            f32x4 acc = (f32x4){0.f, 0.f, 0.f, 0.f};
            acc = __builtin_amdgcn_mfma_f32_16x16x32_bf16(a0, fh[nt][0], acc, 0, 0, 0);
            acc = __builtin_amdgcn_mfma_f32_16x16x32_bf16(a1, fh[nt][1], acc, 0, 0, 0);
            acc = __builtin_amdgcn_mfma_f32_16x16x32_bf16(a0, fl[nt][0], acc, 0, 0, 0);
            acc = __builtin_amdgcn_mfma_f32_16x16x32_bf16(a1, fl[nt][1], acc, 0, 0, 0);
            float e0 = __expf(acc[0] - Mv[nt]);
            float e1 = __expf(acc[1] - Mv[nt]);
            float e2 = __expf(acc[2] - Mv[nt]);
            float e3 = __expf(acc[3] - Mv[nt]);
            zacc[nt] += (e0 + e1) + (e2 + e3);
            // E in-register as GEMM2 B-frag (k=8q+j -> s=16w+4q+j, j<4)
            bfrag Bf = {(short)f2bf(e0), (short)f2bf(e1),
                        (short)f2bf(e2), (short)f2bf(e3), 0, 0, 0, 0};
            #pragma unroll
            for (int it = 0; it < 4; it++)
                Uacc[it * 4 + nt] =
                    __builtin_amdgcn_mfma_f32_16x16x32_bf16(A8[it], Bf, Uacc[it * 4 + nt], 0, 0, 0);
        }
    }

    // ---- merge the 4 wave partials through LDS (round 7's verified epilogue)
    float* mg  = (float*)smem;              // [4][4096]
    float* zsh = (float*)(smem + 65536);
    #pragma unroll
    for (int e = 0; e < 16; e++) {
        #pragma unroll
        for (int r = 0; r < 4; r++)
            mg[w * 4096 + (e * 4 + r) * 64 + lane] = Uacc[e][r];
    }
    #pragma unroll
    for (int nt = 0; nt < 4; nt++) {
        float v = zacc[nt];
        v += __shfl_down(v, 32, 64);
        v += __shfl_down(v, 16, 64);
        if (quad == 0) zsh[w * 64 + nt * 16 + x] = v;
    }
    __syncthreads();

    float* Up = ws + UP_F;
    #pragma unroll
    for (int k = 0; k < 16; k++) {
        int idx = k * 256 + t;
        int e  = idx >> 6;                  // reg slot ((it*4+nt)*4+r)
        int ln = idx & 63;
        int it = e >> 4, nt = (e >> 2) & 3, r = e & 3;
        int i  = it * 16 + (ln >> 4) * 4 + r;
        int b  = nt * 16 + (ln & 15);
        float s = mg[idx] + mg[4096 + idx] + mg[8192 + idx] + mg[12288 + idx];
        Up[((btile * 64 + i) * 64 + chunk) * 64 + b] = s;
    }
    if (t < 64) {
        float z = zsh[t] + zsh[64 + t] + zsh[128 + t] + zsh[192 + t];
        (ws + ZP_F)[(btile * 64 + chunk) * 64 + t] = z;
    }
    if (blockIdx.x == 0 && t == 0) out[0] = 0.f;   // before finalize dispatch
}

// ---------------------------------------------------------------------------
// Finalize (separate dispatch = coherence boundary): sum 64 chunk partials,
// p = U/Z, clamp, write out[1..]; masked BCE (log clamp -100), block reduce,
// atomicAdd loss into out[0].
__global__ __launch_bounds__(256) void finalize_kernel(
    const float* __restrict__ ws, const float* __restrict__ y,
    const float* __restrict__ mask, float* __restrict__ out) {
    const int i     = blockIdx.x >> 1;
    const int b     = ((blockIdx.x & 1) << 8) + threadIdx.x;
    const int btile = b >> 6;
    const int bl    = b & 63;

    const float* zp = ws + ZP_F + (btile * 64) * 64 + bl;
    const float* up = ws + UP_F + ((btile * 64 + i) * 64) * 64 + bl;
    float z = 0.f, u = 0.f;
    #pragma unroll 8
    for (int c = 0; c < 64; c++) { z += zp[c * 64]; u += up[c * 64]; }

    float p = fminf(fmaxf(u / z, 0.f), 1.f);
    const int idx = b * 64 + i;
    out[1 + idx] = p;

    float lp  = fmaxf(logf(p), -100.f);
    float l1p = fmaxf(logf(1.f - p), -100.f);
    float yy = y[idx];
    float bce = -(yy * lp + (1.f - yy) * l1p) * mask[idx] * (1.f / (float)N_BATCH);

    float v = bce;
    #pragma unroll
    for (int off = 32; off > 0; off >>= 1) v += __shfl_down(v, off, 64);
    __shared__ float wsum[4];
    if ((threadIdx.x & 63) == 0) wsum[threadIdx.x >> 6] = v;
    __syncthreads();
    if (threadIdx.x == 0)
        atomicAdd(&out[0], wsum[0] + wsum[1] + wsum[2] + wsum[3]);
}

// ---------------------------------------------------------------------------
extern "C" void kernel_launch(void* const* d_in, const int* in_sizes, int n_in,
                              void* d_out, int out_size, void* d_ws, size_t ws_size,
                              hipStream_t stream) {
    const float* f    = (const float*)d_in[0];   // [512, 64]
    const float* S    = (const float*)d_in[1];   // [32768, 64]
    const float* y    = (const float*)d_in[2];   // [512, 64]
    const float* mask = (const float*)d_in[3];   // [512, 64]
    float* out = (float*)d_out;                  // [1 + 512*64]
    float* ws  = (float*)d_ws;

    fused_kernel<<<512, 256, 0, stream>>>(f, S, ws, out);
    finalize_kernel<<<128, 256, 0, stream>>>(ws, y, mask, out);
}